// Round 7
// baseline (639.250 us; speedup 1.0000x reference)
//
#include <hip/hip_runtime.h>
#include <math.h>

typedef unsigned long long u64;
typedef unsigned int u32;
typedef unsigned short u16;
typedef unsigned char u8;

#define N_NODES    50000
#define N_G_EDGES  400000
#define N_LG_EDGES 600000
#define OUT_FEATS  64
#define EPSV       0.001f
#define PI_F       3.14159265358979323846f
#define HPI_F      1.57079632679489662f
#define FXSCALE    512.0f
#define INV_FXSCALE (1.0f/512.0f)

#define NBLK 256
#define NTHR 1024

// histogram decomposition: 16 sample-chunks x 16 bin-ranges = 256 blocks
#define CHUNKS   16
#define RANGES   16
#define GBINS_R  3125        // 50000/16
#define GWORDS   782
#define GSTRIDE  784
#define LGBINS_R 25000       // 400000/16
#define LGWORDS  6250

// scatter
#define NBUCK 256
#define NPB   196            // nodes per bucket
#define SPB   (NPB*4)        // 784 slots
#define EPB   2344           // edges per block (256*2344 = 600064)
#define BCAP  4096           // per-bucket region capacity (load ~2344, +36 sigma margin)

// ws layout (bytes):
//   kk8  u8 [400000]       @ 0           (  400,000)
//   R    u64[400000]       @ 400,000     (3,200,000)
//   cg   u32[256*784]      @ 3,600,000   (  802,816)
//   clg  u32[256*6250]     @ 4,402,816   (6,400,000)
//   invg f32[50000]        @ 10,802,816  (  200,000)
//   gbase u32[256]         @ 11,002,816  (    1,024)
//   sarr u16[256*4096]     @ 11,003,840  (2,097,152)
//   qarr u64[256*4096]     @ 13,100,992  (8,388,608)
// total 21,489,600 bytes

__device__ u32 g_bar_cnt = 0;
__device__ u32 g_bar_sense = 0;

__device__ __forceinline__ void grid_sync(u32* my_sense) {
    __threadfence();
    __syncthreads();
    if (threadIdx.x == 0) {
        u32 want = *my_sense ^ 1u;
        u32 old = __hip_atomic_fetch_add(&g_bar_cnt, 1u, __ATOMIC_ACQ_REL,
                                         __HIP_MEMORY_SCOPE_AGENT);
        if (old == NBLK - 1) {
            __hip_atomic_store(&g_bar_cnt, 0u, __ATOMIC_RELAXED, __HIP_MEMORY_SCOPE_AGENT);
            __hip_atomic_store(&g_bar_sense, want, __ATOMIC_RELEASE, __HIP_MEMORY_SCOPE_AGENT);
        } else {
            while (__hip_atomic_load(&g_bar_sense, __ATOMIC_ACQUIRE,
                                     __HIP_MEMORY_SCOPE_AGENT) != want) {
                __builtin_amdgcn_s_sleep(2);
            }
        }
        *my_sense = want;
    }
    __syncthreads();
    __threadfence();
}

__global__ __launch_bounds__(NTHR) void fused_all(
    const int* __restrict__ an, const int* __restrict__ gsrc,
    const int* __restrict__ gdst, const int* __restrict__ lgsrc,
    const int* __restrict__ lgdst, const float* __restrict__ costheta,
    const float* __restrict__ dnr, const float* __restrict__ pa,
    const float* __restrict__ pb, const float* __restrict__ pc,
    const float* __restrict__ pd, const float* __restrict__ VT,
    u8* __restrict__ kk8, u64* __restrict__ R, u32* __restrict__ cg,
    u32* __restrict__ clg, float* __restrict__ invg, u32* __restrict__ gbase,
    u16* __restrict__ sarr, u64* __restrict__ qarr, float* __restrict__ out)
{
    __shared__ u32 hist[LGWORDS];   // 25 KB
    __shared__ u32 lcnt[NBUCK];
    __shared__ u32 bbase[NBUCK];
    __shared__ u64 ts[SPB];         // 6.3 KB
    __shared__ float vt_s[1024];
    __shared__ float invg_s[NPB];

    const int tid = threadIdx.x;
    const int bid = blockIdx.x;
    u32 my_sense = __hip_atomic_load(&g_bar_sense, __ATOMIC_RELAXED,
                                     __HIP_MEMORY_SCOPE_AGENT);

    // ============ P0: gbase zero, kk8 pack, both histograms ============
    if (bid == 0 && tid < NBUCK) gbase[tid] = 0u;
    for (int g = bid * NTHR + tid; g < N_G_EDGES; g += NBLK * NTHR)
        kk8[g] = (u8)(an[gsrc[g]] | (an[gdst[g]] << 4));

    const int c = bid & (CHUNKS - 1);
    const int r = bid >> 4;

    for (int w = tid; w < GWORDS; w += NTHR) hist[w] = 0u;
    __syncthreads();
    {
        const int lo = r * GBINS_R;
        const int s0 = c * (N_G_EDGES / CHUNKS);
        const int s1 = s0 + (N_G_EDGES / CHUNKS);
        for (int g = s0 + tid; g < s1; g += NTHR) {
            unsigned lb = (unsigned)(gsrc[g] - lo);
            if (lb < (unsigned)GBINS_R)
                atomicAdd(&hist[lb >> 2], 1u << (8 * (lb & 3)));
        }
    }
    __syncthreads();
    for (int w = tid; w < GWORDS; w += NTHR) cg[bid * GSTRIDE + w] = hist[w];
    __syncthreads();

    for (int w = tid; w < LGWORDS; w += NTHR) hist[w] = 0u;
    __syncthreads();
    {
        const int lo = r * LGBINS_R;
        const int s0 = c * (N_LG_EDGES / CHUNKS);
        const int s1 = s0 + (N_LG_EDGES / CHUNKS);
        for (int e = s0 + tid; e < s1; e += NTHR) {
            unsigned lb = (unsigned)(lgsrc[e] - lo);
            if (lb < (unsigned)LGBINS_R)
                atomicAdd(&hist[lb >> 2], 1u << (8 * (lb & 3)));
        }
    }
    __syncthreads();
    for (int w = tid; w < LGWORDS; w += NTHR) clg[bid * LGWORDS + w] = hist[w];

    grid_sync(&my_sense);

    // ============ P1: R records + inv_g ============
    for (int g = bid * NTHR + tid; g < N_G_EDGES; g += NBLK * NTHR) {
        int r_ = g / LGBINS_R;
        int lb = g - r_ * LGBINS_R;
        int w = lb >> 2, sh = 8 * (lb & 3);
        const u32* base = clg + (size_t)(r_ * CHUNKS) * LGWORDS + w;
        u32 cnt = 0;
#pragma unroll
        for (int cc = 0; cc < CHUNKS; ++cc) cnt += (base[cc * LGWORDS] >> sh) & 0xffu;
        float inv = 1.0f / (float)(cnt < 1u ? 1u : cnt);
        R[g] = ((u64)__float_as_uint(inv) << 32) | ((u64)(u32)gsrc[g] << 8) | (u64)kk8[g];
    }
    for (int n = bid * NTHR + tid; n < N_NODES; n += NBLK * NTHR) {
        int r_ = n / GBINS_R;
        int lb = n - r_ * GBINS_R;
        int w = lb >> 2, sh = 8 * (lb & 3);
        const u32* base = cg + (size_t)(r_ * CHUNKS) * GSTRIDE + w;
        u32 cnt = 0;
#pragma unroll
        for (int cc = 0; cc < CHUNKS; ++cc) cnt += (base[cc * GSTRIDE] >> sh) & 0xffu;
        invg[n] = 1.0f / (float)(cnt < 1u ? 1u : cnt);
    }

    grid_sync(&my_sense);

    // ============ P2: edge compute + exact-reservation scatter ============
    if (tid < NBUCK) lcnt[tid] = 0u;
    __syncthreads();

    const float a0 = pa[0], a1 = pa[1], a2 = pa[2], a3 = pa[3];
    const float B0 = fmodf(pb[0], PI_F), B1 = fmodf(pb[1], PI_F),
                B2 = fmodf(pb[2], PI_F), B3 = fmodf(pb[3], PI_F);
    const float c0 = pc[0], c1 = pc[1], c2 = pc[2], c3 = pc[3];
    const float d0 = pd[0], d1 = pd[1], d2 = pd[2], d3 = pd[3];

    const int e0 = bid * EPB;
    const int e1 = (e0 + EPB < N_LG_EDGES) ? e0 + EPB : N_LG_EDGES;
    u64 q0 = 0, q1 = 0, q2 = 0;
    u32 m0 = 0, m1 = 0, m2 = 0;

#define COMPUTE_EDGE(IT, QV, MV)                                                  \
    {                                                                             \
        int e = e0 + IT * NTHR + tid;                                             \
        if (e < e1) {                                                             \
            u64 rr = R[lgsrc[e]];                                                 \
            int ka = (int)(rr & 0xf);                                             \
            int kb = (int)((rr >> 4) & 0xf);                                      \
            int node = (int)((rr >> 8) & 0xffff);                                 \
            float inv = __uint_as_float((u32)(rr >> 32));                         \
            int kd = kk8[lgdst[e]] >> 4;                                          \
            int key = ((ka == kd) ? 2 : 0) + ((kb == ka && kb == kd) ? 1 : 0);    \
            float ct = fminf(fmaxf(costheta[e], -EPSV), EPSV);                    \
            float theta = HPI_F - ct;                                             \
            float dn2 = dnr[e]; dn2 *= dn2;                                       \
            float s = inv * FXSCALE;                                              \
            u64 q;                                                                \
            q  = (u64)(u32)(__powf((__cosf(a0*theta+B0)+1.f)*.5f, c0) * __expf(-d0*dn2) * s + .5f);        \
            q |= (u64)(u32)(__powf((__cosf(a1*theta+B1)+1.f)*.5f, c1) * __expf(-d1*dn2) * s + .5f) << 16;  \
            q |= (u64)(u32)(__powf((__cosf(a2*theta+B2)+1.f)*.5f, c2) * __expf(-d2*dn2) * s + .5f) << 32;  \
            q |= (u64)(u32)(__powf((__cosf(a3*theta+B3)+1.f)*.5f, c3) * __expf(-d3*dn2) * s + .5f) << 48;  \
            int bucket = node / NPB;                                              \
            int slot = (node - bucket * NPB) * 4 + key;                           \
            u32 rank = atomicAdd(&lcnt[bucket], 1u);                              \
            QV = q;                                                               \
            MV = 0x80000000u | (rank << 18) | ((u32)bucket << 10) | (u32)slot;    \
        }                                                                         \
    }

    COMPUTE_EDGE(0, q0, m0)
    COMPUTE_EDGE(1, q1, m1)
    COMPUTE_EDGE(2, q2, m2)
#undef COMPUTE_EDGE

    __syncthreads();
    if (tid < NBUCK) {
        u32 v = lcnt[tid];
        bbase[tid] = v ? atomicAdd(&gbase[tid], v) : 0u;
    }
    __syncthreads();

#define WRITE_EDGE(QV, MV)                                                        \
    if (MV & 0x80000000u) {                                                       \
        u32 bk = (MV >> 10) & 0xffu;                                              \
        u32 pos = bbase[bk] + ((MV >> 18) & 0x1fffu);                             \
        size_t idx = (size_t)bk * BCAP + pos;                                     \
        qarr[idx] = QV;                                                           \
        sarr[idx] = (u16)(MV & 0x3ffu);                                           \
    }
    WRITE_EDGE(q0, m0)
    WRITE_EDGE(q1, m1)
    WRITE_EDGE(q2, m2)
#undef WRITE_EDGE

    grid_sync(&my_sense);

    // ============ P3: per-bucket gather + fused output ============
    for (int i = tid; i < SPB; i += NTHR) ts[i] = 0ull;
    vt_s[tid] = VT[tid];
    if (tid < NPB) {
        int n = bid * NPB + tid;
        invg_s[tid] = (n < N_NODES) ? invg[n] : 0.0f;
    }
    __syncthreads();

    const u32 total = gbase[bid];
    const u64* qb = qarr + (size_t)bid * BCAP;
    const u16* sb = sarr + (size_t)bid * BCAP;
    for (u32 i = tid; i < total; i += NTHR)
        atomicAdd(&ts[sb[i]], qb[i]);
    __syncthreads();

    for (int j = tid; j < NPB * OUT_FEATS; j += NTHR) {
        int nl = j >> 6, f = j & 63;
        int n = bid * NPB + nl;
        if (n < N_NODES) {
            float acc = 0.0f;
#pragma unroll
            for (int k = 0; k < 4; ++k) {
                u64 t = ts[nl * 4 + k];
#pragma unroll
                for (int h = 0; h < 4; ++h)
                    acc += vt_s[k * 256 + f * 4 + h] * (float)((u32)(t >> (16 * h)) & 0xffffu);
            }
            out[n * OUT_FEATS + f] = acc * (INV_FXSCALE * invg_s[nl]);
        }
    }
}

extern "C" void kernel_launch(void* const* d_in, const int* in_sizes, int n_in,
                              void* d_out, int out_size, void* d_ws, size_t ws_size,
                              hipStream_t stream) {
    const int*   an       = (const int*)d_in[0];
    const int*   gsrc     = (const int*)d_in[1];
    const int*   gdst     = (const int*)d_in[2];
    const int*   lgsrc    = (const int*)d_in[3];
    const int*   lgdst    = (const int*)d_in[4];
    const float* costheta = (const float*)d_in[5];
    const float* dnr      = (const float*)d_in[6];
    const float* pa       = (const float*)d_in[7];
    const float* pb       = (const float*)d_in[8];
    const float* pc       = (const float*)d_in[9];
    const float* pd       = (const float*)d_in[10];
    const float* vt       = (const float*)d_in[11];
    float* out = (float*)d_out;

    char* ws = (char*)d_ws;
    u8*    kk8   = (u8*) (ws + 0);
    u64*   R     = (u64*)(ws + 400000);
    u32*   cg    = (u32*)(ws + 3600000);
    u32*   clg   = (u32*)(ws + 4402816);
    float* invg  = (float*)(ws + 10802816);
    u32*   gbase = (u32*)(ws + 11002816);
    u16*   sarr  = (u16*)(ws + 11003840);
    u64*   qarr  = (u64*)(ws + 13100992);

    fused_all<<<dim3(NBLK), dim3(NTHR), 0, stream>>>(
        an, gsrc, gdst, lgsrc, lgdst, costheta, dnr, pa, pb, pc, pd, vt,
        kk8, R, cg, clg, invg, gbase, sarr, qarr, out);
}

// Round 8
// 214.335 us; speedup vs baseline: 2.9825x; 2.9825x over previous
//
#include <hip/hip_runtime.h>
#include <math.h>

typedef unsigned long long u64;
typedef unsigned int u32;
typedef unsigned short u16;
typedef unsigned char u8;

#define N_NODES    50000
#define N_G_EDGES  400000
#define N_LG_EDGES 600000
#define OUT_FEATS  64
#define EPSV       0.001f
#define PI_F       3.14159265358979323846f
#define FXSCALE    512.0f
#define INV_FXSCALE (1.0f/512.0f)

// kA2 job split: 256 blocks
//   blocks [0,64):   lg-histogram, each owns 6250 bins, scans all lgsrc
//   blocks [64,80):  g-histogram, each owns 3125 node bins, scans all gsrc
//   blocks [80,256): kk8 packing over g-edges
#define LG_HB     64
#define LG_BPB    6250       // 64*6250 = 400000
#define LG_WPB    1563       // ceil(6250/4)
#define G_HB      16
#define G_BPB     3125       // 16*3125 = 50000
#define G_WPB     782
#define KB0       80
#define KB_N      176
#define KB_GPB    2273       // 176*2273 = 400048 >= 400000

// scatter (proven R6 machinery)
#define NBUCK 256
#define NPB   196            // nodes per bucket (bucket = node/196)
#define SPB   (NPB*4)        // 784 slots per bucket
#define CAP   40             // per-(block,bucket) cell capacity (~Poisson(9.2)+10sigma)
#define EPB   2344           // edges per scatter block (256*2344 >= 600000)
#define ENT   (NBUCK*CAP)    // 10240 entries per bucket region

// ws layout (bytes):
//   kk8   u8 [400000]      @ 0          (  400,000)
//   invlg f32[400000]      @ 400,000    (1,600,000)
//   invg  f32[50000]       @ 2,000,000  (  200,000)
//   cnt   u32[256*256]     @ 2,200,000  (  262,144)
//   sarr  u16[256*10240]   @ 2,462,144  (5,242,880)
//   qarr  u64[256*10240]   @ 7,705,024  (20,971,520)
// total 28,676,544 bytes

// ---------------- kA2: full-range histograms + kk8 pack (job-split) --------
__global__ __launch_bounds__(1024) void kA2(const int* __restrict__ an,
                                            const int* __restrict__ gsrc,
                                            const int* __restrict__ gdst,
                                            const int* __restrict__ lgsrc,
                                            u8*  __restrict__ kk8,
                                            float* __restrict__ invlg,
                                            float* __restrict__ invg) {
    __shared__ u32 hist[LG_WPB];   // 6.3 KB, u8-packed counts
    const int tid = threadIdx.x;
    const int bid = blockIdx.x;

    if (bid < LG_HB) {
        // lg-edge counts for bins [lo, lo+6250)
        const int lo = bid * LG_BPB;
        for (int w = tid; w < LG_WPB; w += 1024) hist[w] = 0u;
        __syncthreads();
        for (int e = tid; e < N_LG_EDGES; e += 1024) {
            unsigned lb = (unsigned)(lgsrc[e] - lo);
            if (lb < (unsigned)LG_BPB)
                atomicAdd(&hist[lb >> 2], 1u << (8 * (lb & 3)));
        }
        __syncthreads();
        for (int i = tid; i < LG_BPB; i += 1024) {
            u32 c = (hist[i >> 2] >> (8 * (i & 3))) & 0xffu;
            invlg[lo + i] = 1.0f / (float)(c < 1u ? 1u : c);
        }
    } else if (bid < KB0) {
        // node degree counts for bins [lo, lo+3125)
        const int lo = (bid - LG_HB) * G_BPB;
        for (int w = tid; w < G_WPB; w += 1024) hist[w] = 0u;
        __syncthreads();
        for (int g = tid; g < N_G_EDGES; g += 1024) {
            unsigned lb = (unsigned)(gsrc[g] - lo);
            if (lb < (unsigned)G_BPB)
                atomicAdd(&hist[lb >> 2], 1u << (8 * (lb & 3)));
        }
        __syncthreads();
        for (int i = tid; i < G_BPB; i += 1024) {
            int n = lo + i;
            if (n < N_NODES) {
                u32 c = (hist[i >> 2] >> (8 * (i & 3))) & 0xffu;
                invg[n] = 1.0f / (float)(c < 1u ? 1u : c);
            }
        }
    } else {
        // kk8 packing for g-edge range
        const int g0 = (bid - KB0) * KB_GPB;
        const int g1 = (g0 + KB_GPB < N_G_EDGES) ? g0 + KB_GPB : N_G_EDGES;
        for (int g = g0 + tid; g < g1; g += 1024)
            kk8[g] = (u8)(an[gsrc[g]] | (an[gdst[g]] << 4));
    }
}

// ---------------- kC1: edge compute + CAP-mailbox scatter (R6-proven) ------
__global__ __launch_bounds__(1024, 1) void kC1(const int* __restrict__ lgsrc,
                                               const int* __restrict__ lgdst,
                                               const int* __restrict__ gsrc,
                                               const float* __restrict__ costheta,
                                               const float* __restrict__ dnr,
                                               const float* __restrict__ pa,
                                               const float* __restrict__ pb,
                                               const float* __restrict__ pc,
                                               const float* __restrict__ pd,
                                               const u8*  __restrict__ kk8,
                                               const float* __restrict__ invlg,
                                               u64* __restrict__ qarr,
                                               u16* __restrict__ sarr,
                                               u32* __restrict__ cnt) {
    __shared__ u32 lcnt[NBUCK];
    const int tid = threadIdx.x;
    const int bid = blockIdx.x;
    if (tid < NBUCK) lcnt[tid] = 0u;
    __syncthreads();

    const int e0 = bid * EPB;
    const int e1 = (e0 + EPB < N_LG_EDGES) ? e0 + EPB : N_LG_EDGES;
    for (int e = e0 + tid; e < e1; e += 1024) {
        int ls = lgsrc[e];
        int ld = lgdst[e];
        u32 ks = kk8[ls];
        int ka = (int)(ks & 0xfu);
        int kb = (int)(ks >> 4);
        int kd = kk8[ld] >> 4;
        int node = gsrc[ls];
        float inv = invlg[ls];
        int key = ((ka == kd) ? 2 : 0) + ((kb == ka && kb == kd) ? 1 : 0);

        float ct = fminf(fmaxf(costheta[e], -EPSV), EPSV);
        float theta = acosf(ct);
        float dn = dnr[e];
        float dn2 = dn * dn;

        u64 q = 0;
#pragma unroll
        for (int h = 0; h < 4; ++h) {
            float B = fmodf(pb[h], PI_F);
            float ang = __powf((__cosf(pa[h] * theta + B) + 1.0f) * 0.5f, pc[h]);
            float rad = __expf(-pd[h] * dn2);
            float sp = rad * ang * inv;  // in [0,1]
            q |= (u64)(u32)(sp * FXSCALE + 0.5f) << (16 * h);
        }

        int bucket = node / NPB;                    // 0..255
        int slot = (node - bucket * NPB) * 4 + key; // 0..783
        u32 rank = atomicAdd(&lcnt[bucket], 1u);
        if (rank < CAP) {
            size_t pos = (size_t)bucket * ENT + bid * CAP + rank;
            qarr[pos] = q;
            sarr[pos] = (u16)slot;
        }
    }
    __syncthreads();
    if (tid < NBUCK) {
        u32 v = lcnt[tid];
        cnt[tid * NBUCK + bid] = (v < CAP) ? v : (u32)CAP;
    }
}

// ---------------- kC2: per-bucket gather + fused output (R6-proven) --------
__global__ __launch_bounds__(1024, 1) void kC2(const u64* __restrict__ qarr,
                                               const u16* __restrict__ sarr,
                                               const u32* __restrict__ cnt,
                                               const float* __restrict__ inv_g,
                                               const float* __restrict__ VT,
                                               float* __restrict__ out) {
    __shared__ u64 ts[SPB];
    __shared__ u32 c[NBUCK];
    __shared__ float vt_s[1024];
    const int tid = threadIdx.x;
    const int b = blockIdx.x;

    for (int i = tid; i < SPB; i += 1024) ts[i] = 0ull;
    if (tid < NBUCK) c[tid] = cnt[b * NBUCK + tid];
    vt_s[tid] = VT[tid];  // 4*256 = 1024 floats
    __syncthreads();

    const u64* qb = qarr + (size_t)b * ENT;
    const u16* sb = sarr + (size_t)b * ENT;
    for (int i = tid; i < ENT; i += 1024) {
        int blk = i / CAP;
        int rank = i - blk * CAP;
        if ((u32)rank < c[blk]) {
            u64 q = qb[i];
            int s = sb[i];
            atomicAdd(&ts[s], q);
        }
    }
    __syncthreads();

    const int n0 = b * NPB;
    for (int j = tid; j < NPB * OUT_FEATS; j += 1024) {
        int nl = j >> 6;
        int f = j & 63;
        int n = n0 + nl;
        if (n < N_NODES) {
            float acc = 0.0f;
#pragma unroll
            for (int k = 0; k < 4; ++k) {
                u64 t = ts[nl * 4 + k];
#pragma unroll
                for (int h = 0; h < 4; ++h) {
                    float tv = (float)((u32)(t >> (16 * h)) & 0xffffu);
                    acc += vt_s[k * 256 + f * 4 + h] * tv;
                }
            }
            out[n * OUT_FEATS + f] = acc * INV_FXSCALE * inv_g[n];
        }
    }
}

extern "C" void kernel_launch(void* const* d_in, const int* in_sizes, int n_in,
                              void* d_out, int out_size, void* d_ws, size_t ws_size,
                              hipStream_t stream) {
    const int*   an       = (const int*)d_in[0];
    const int*   gsrc     = (const int*)d_in[1];
    const int*   gdst     = (const int*)d_in[2];
    const int*   lgsrc    = (const int*)d_in[3];
    const int*   lgdst    = (const int*)d_in[4];
    const float* costheta = (const float*)d_in[5];
    const float* dnr      = (const float*)d_in[6];
    const float* pa       = (const float*)d_in[7];
    const float* pb       = (const float*)d_in[8];
    const float* pc       = (const float*)d_in[9];
    const float* pd       = (const float*)d_in[10];
    const float* vt       = (const float*)d_in[11];
    float* out = (float*)d_out;

    char* ws = (char*)d_ws;
    u8*    kk8   = (u8*)  (ws + 0);
    float* invlg = (float*)(ws + 400000);
    float* invg  = (float*)(ws + 2000000);
    u32*   cnt   = (u32*) (ws + 2200000);
    u16*   sarr  = (u16*) (ws + 2462144);
    u64*   qarr  = (u64*) (ws + 7705024);

    kA2<<<dim3(256), dim3(1024), 0, stream>>>(
        an, gsrc, gdst, lgsrc, kk8, invlg, invg);
    kC1<<<dim3(256), dim3(1024), 0, stream>>>(
        lgsrc, lgdst, gsrc, costheta, dnr, pa, pb, pc, pd, kk8, invlg,
        qarr, sarr, cnt);
    kC2<<<dim3(256), dim3(1024), 0, stream>>>(
        qarr, sarr, cnt, invg, vt, out);
}

// Round 9
// 60.111 us; speedup vs baseline: 10.6345x; 3.5657x over previous
//
#include <hip/hip_runtime.h>
#include <math.h>

typedef unsigned long long u64;
typedef unsigned int u32;
typedef unsigned short u16;
typedef unsigned char u8;

#define N_NODES    50000
#define N_G_EDGES  400000
#define N_LG_EDGES 600000
#define OUT_FEATS  64
#define EPSV       0.001f
#define PI_F       3.14159265358979323846f
#define HPI_F      1.57079632679489662f
#define FXSCALE    512.0f
#define INV_FXSCALE (1.0f/512.0f)

// kH roles: 256 blocks
//   [0,128):   lg histogram, 16 chunks x 8 ranges; chunk=bid&15, range=bid>>4
//   [128,144): g histogram, 16 chunks x full 50k-bin range
//   [144,256): kk8 packing
#define LG_CH   16
#define LG_RG   8
#define LG_BINS 50000
#define LG_W    12500      // u32 words (u8-packed), 50 KB LDS
#define LG_EPC  37500      // 600000/16
#define GH_B0   128
#define GH_CH   16
#define GH_W    12500      // 50000 bins u8-packed
#define GH_EPC  25000      // 400000/16
#define PK_B0   144
#define PK_GPB  3572       // 112*3572 = 400064

// scatter (R6-proven mailbox)
#define NBUCK 256
#define NPB   196
#define SPB   (NPB*4)
#define CAP   40
#define EPB   2344
#define ENT   (NBUCK*CAP)

// ws layout (bytes):
//   kk8  u8 [400000]      @ 0           (   400,000)
//   R    u64[400000]      @ 400,000     ( 3,200,000)
//   clg  u32[128*12500]   @ 3,600,000   ( 6,400,000)
//   cg   u32[16*12500]    @ 10,000,000  (   800,000)
//   invg f32[50000]       @ 10,800,000  (   200,000)
//   cnt  u32[256*256]     @ 11,000,000  (   262,144)
//   sarr u16[256*10240]   @ 11,262,144  ( 5,242,880)
//   qarr u64[256*10240]   @ 16,505,024  (20,971,520)
// total 37,476,544

// ---------------- kH: balanced histograms + kk8 pack ----------------------
__global__ __launch_bounds__(1024) void kH(const int* __restrict__ an,
                                           const int* __restrict__ gsrc,
                                           const int* __restrict__ gdst,
                                           const int* __restrict__ lgsrc,
                                           u8*  __restrict__ kk8,
                                           u32* __restrict__ clg,
                                           u32* __restrict__ cg) {
    __shared__ u32 hist[LG_W];   // 50 KB
    const int tid = threadIdx.x;
    const int bid = blockIdx.x;

    if (bid < GH_B0) {
        const int cc = bid & 15, r = bid >> 4;
        const int lo = r * LG_BINS;
        for (int w = tid; w < LG_W; w += 1024) hist[w] = 0u;
        __syncthreads();
        const int s0 = cc * LG_EPC;
        for (int e = s0 + tid; e < s0 + LG_EPC; e += 1024) {
            unsigned lb = (unsigned)(lgsrc[e] - lo);
            if (lb < (unsigned)LG_BINS)
                atomicAdd(&hist[lb >> 2], 1u << (8 * (lb & 3)));
        }
        __syncthreads();
        u32* dst = clg + (size_t)bid * LG_W;
        for (int w = tid; w < LG_W; w += 1024) dst[w] = hist[w];
    } else if (bid < PK_B0) {
        const int cc = bid - GH_B0;
        for (int w = tid; w < GH_W; w += 1024) hist[w] = 0u;
        __syncthreads();
        const int s0 = cc * GH_EPC;
        for (int g = s0 + tid; g < s0 + GH_EPC; g += 1024) {
            int n = gsrc[g];
            atomicAdd(&hist[n >> 2], 1u << (8 * (n & 3)));
        }
        __syncthreads();
        u32* dst = cg + (size_t)cc * GH_W;
        for (int w = tid; w < GH_W; w += 1024) dst[w] = hist[w];
    } else {
        const int g0 = (bid - PK_B0) * PK_GPB;
        const int g1 = (g0 + PK_GPB < N_G_EDGES) ? g0 + PK_GPB : N_G_EDGES;
        for (int g = g0 + tid; g < g1; g += 1024)
            kk8[g] = (u8)(an[gsrc[g]] | (an[gdst[g]] << 4));
    }
}

// ---------------- kB: R records + inv_g -----------------------------------
__global__ __launch_bounds__(1024) void kB(const int* __restrict__ gsrc,
                                           const u8*  __restrict__ kk8,
                                           const u32* __restrict__ clg,
                                           const u32* __restrict__ cg,
                                           u64* __restrict__ R,
                                           float* __restrict__ invg) {
    const int i = blockIdx.x * 1024 + threadIdx.x;
    for (int g = i; g < N_G_EDGES; g += 256 * 1024) {
        int r = g / LG_BINS, lb = g - r * LG_BINS;
        int w = lb >> 2, sh = 8 * (lb & 3);
        const u32* base = clg + (size_t)(r * LG_CH) * LG_W + w;
        u32 c = 0;
#pragma unroll
        for (int cc = 0; cc < LG_CH; ++cc) c += (base[(size_t)cc * LG_W] >> sh) & 0xffu;
        float inv = 1.0f / (float)(c < 1u ? 1u : c);
        R[g] = ((u64)__float_as_uint(inv) << 32) | ((u64)(u32)gsrc[g] << 8) | (u64)kk8[g];
    }
    for (int n = i; n < N_NODES; n += 256 * 1024) {
        int w = n >> 2, sh = 8 * (n & 3);
        u32 c = 0;
#pragma unroll
        for (int cc = 0; cc < GH_CH; ++cc) c += (cg[(size_t)cc * GH_W + w] >> sh) & 0xffu;
        invg[n] = 1.0f / (float)(c < 1u ? 1u : c);
    }
}

// ---------------- kC1: edge compute (Taylor angular) + mailbox scatter ----
__global__ __launch_bounds__(1024, 1) void kC1(const int* __restrict__ lgsrc,
                                               const int* __restrict__ lgdst,
                                               const float* __restrict__ costheta,
                                               const float* __restrict__ dnr,
                                               const float* __restrict__ pa,
                                               const float* __restrict__ pb,
                                               const float* __restrict__ pc,
                                               const float* __restrict__ pd,
                                               const u8*  __restrict__ kk8,
                                               const u64* __restrict__ R,
                                               u64* __restrict__ qarr,
                                               u16* __restrict__ sarr,
                                               u32* __restrict__ cnt) {
    __shared__ u32 lcnt[NBUCK];
    const int tid = threadIdx.x;
    const int bid = blockIdx.x;
    if (tid < NBUCK) lcnt[tid] = 0u;

    // Per-head quadratic Taylor of angular term around K = a*pi/2 + B.
    // theta = acos(clip(ct)) = pi/2 - ct exactly to fp32 (|ct|<=1e-3).
    // ang(delta) = ((cos(K + a*delta)+1)/2)^c ~= A0 + A1*delta + A2*delta^2,
    // delta = -ct. Truncation error <= ~1e-6 << 1/512 quantum.
    float A0[4], A1[4], A2[4], DD[4];
#pragma unroll
    for (int h = 0; h < 4; ++h) {
        float a = pa[h], B = fmodf(pb[h], PI_F), c = pc[h], d = pd[h];
        float K = a * HPI_F + B;
        float ck = cosf(K), sk = sinf(K);
        float u0 = 0.5f * (1.0f + ck);
        float f0 = powf(u0, c);
        float g1 = (-0.5f * a * sk) / u0;
        float u2 = -0.25f * a * a * ck;
        float g2 = u2 / u0 - 0.5f * g1 * g1;
        A0[h] = f0;
        A1[h] = f0 * c * g1;
        A2[h] = f0 * (c * g2 + 0.5f * c * c * g1 * g1);
        DD[h] = d;
    }
    __syncthreads();

    const int e0 = bid * EPB;
    const int e1 = (e0 + EPB < N_LG_EDGES) ? e0 + EPB : N_LG_EDGES;
    for (int e = e0 + tid; e < e1; e += 1024) {
        u64 r = R[lgsrc[e]];
        int ka = (int)(r & 0xf);
        int kb = (int)((r >> 4) & 0xf);
        int node = (int)((r >> 8) & 0xffff);
        float inv = __uint_as_float((u32)(r >> 32));
        int kd = kk8[lgdst[e]] >> 4;
        int key = ((ka == kd) ? 2 : 0) + ((kb == ka && kb == kd) ? 1 : 0);

        float ct = fminf(fmaxf(costheta[e], -EPSV), EPSV);
        float del = -ct;
        float dn2 = dnr[e];
        dn2 *= dn2;
        float s = inv * FXSCALE;

        u64 q = 0;
#pragma unroll
        for (int h = 0; h < 4; ++h) {
            float ang = A0[h] + del * (A1[h] + del * A2[h]);
            float rad = __expf(-DD[h] * dn2);
            q |= (u64)(u32)(ang * rad * s + 0.5f) << (16 * h);
        }

        int bucket = node / NPB;
        int slot = (node - bucket * NPB) * 4 + key;
        u32 rank = atomicAdd(&lcnt[bucket], 1u);
        if (rank < CAP) {
            size_t pos = (size_t)bucket * ENT + bid * CAP + rank;
            qarr[pos] = q;
            sarr[pos] = (u16)slot;
        }
    }
    __syncthreads();
    if (tid < NBUCK) {
        u32 v = lcnt[tid];
        cnt[tid * NBUCK + bid] = (v < CAP) ? v : (u32)CAP;
    }
}

// ---------------- kC2: compacted gather + fused output --------------------
__global__ __launch_bounds__(1024, 1) void kC2(const u64* __restrict__ qarr,
                                               const u16* __restrict__ sarr,
                                               const u32* __restrict__ cnt,
                                               const float* __restrict__ inv_g,
                                               const float* __restrict__ VT,
                                               float* __restrict__ out) {
    __shared__ u64 ts[SPB];
    __shared__ u32 pref[257];
    __shared__ float vt_s[1024];
    const int tid = threadIdx.x;
    const int b = blockIdx.x;

    for (int i = tid; i < SPB; i += 1024) ts[i] = 0ull;
    if (tid < 256) pref[tid + 1] = cnt[b * NBUCK + tid];
    if (tid == 0) pref[0] = 0u;
    vt_s[tid] = VT[tid];
    __syncthreads();

    // inclusive scan of pref[1..256]
    for (int off = 1; off < 256; off <<= 1) {
        u32 add = 0;
        if (tid < 256 && tid >= off) add = pref[tid - off + 1];
        __syncthreads();
        if (tid < 256) pref[tid + 1] += add;
        __syncthreads();
    }
    const u32 total = pref[256];

    const u64* qb = qarr + (size_t)b * ENT;
    const u16* sb = sarr + (size_t)b * ENT;
    for (u32 i = tid; i < total; i += 1024) {
        int lo = 0, hi = 256;
        while (hi - lo > 1) {
            int mid = (lo + hi) >> 1;
            if (pref[mid] <= i) lo = mid; else hi = mid;
        }
        u32 rank = i - pref[lo];
        size_t idx = (size_t)lo * CAP + rank;
        atomicAdd(&ts[sb[idx]], qb[idx]);
    }
    __syncthreads();

    const int n0 = b * NPB;
    for (int j = tid; j < NPB * OUT_FEATS; j += 1024) {
        int nl = j >> 6, f = j & 63;
        int n = n0 + nl;
        if (n < N_NODES) {
            float acc = 0.0f;
#pragma unroll
            for (int k = 0; k < 4; ++k) {
                u64 t = ts[nl * 4 + k];
#pragma unroll
                for (int h = 0; h < 4; ++h) {
                    float tv = (float)((u32)(t >> (16 * h)) & 0xffffu);
                    acc += vt_s[k * 256 + f * 4 + h] * tv;
                }
            }
            out[n * OUT_FEATS + f] = acc * INV_FXSCALE * inv_g[n];
        }
    }
}

extern "C" void kernel_launch(void* const* d_in, const int* in_sizes, int n_in,
                              void* d_out, int out_size, void* d_ws, size_t ws_size,
                              hipStream_t stream) {
    const int*   an       = (const int*)d_in[0];
    const int*   gsrc     = (const int*)d_in[1];
    const int*   gdst     = (const int*)d_in[2];
    const int*   lgsrc    = (const int*)d_in[3];
    const int*   lgdst    = (const int*)d_in[4];
    const float* costheta = (const float*)d_in[5];
    const float* dnr      = (const float*)d_in[6];
    const float* pa       = (const float*)d_in[7];
    const float* pb       = (const float*)d_in[8];
    const float* pc       = (const float*)d_in[9];
    const float* pd       = (const float*)d_in[10];
    const float* vt       = (const float*)d_in[11];
    float* out = (float*)d_out;

    char* ws = (char*)d_ws;
    u8*    kk8  = (u8*)  (ws + 0);
    u64*   R    = (u64*) (ws + 400000);
    u32*   clg  = (u32*) (ws + 3600000);
    u32*   cg   = (u32*) (ws + 10000000);
    float* invg = (float*)(ws + 10800000);
    u32*   cnt  = (u32*) (ws + 11000000);
    u16*   sarr = (u16*) (ws + 11262144);
    u64*   qarr = (u64*) (ws + 16505024);

    kH<<<dim3(256), dim3(1024), 0, stream>>>(an, gsrc, gdst, lgsrc, kk8, clg, cg);
    kB<<<dim3(256), dim3(1024), 0, stream>>>(gsrc, kk8, clg, cg, R, invg);
    kC1<<<dim3(256), dim3(1024), 0, stream>>>(
        lgsrc, lgdst, costheta, dnr, pa, pb, pc, pd, kk8, R, qarr, sarr, cnt);
    kC2<<<dim3(256), dim3(1024), 0, stream>>>(qarr, sarr, cnt, invg, vt, out);
}

// Round 10
// 55.152 us; speedup vs baseline: 11.5908x; 1.0899x over previous
//
#include <hip/hip_runtime.h>
#include <math.h>

typedef unsigned long long u64;
typedef unsigned int u32;
typedef unsigned short u16;
typedef unsigned char u8;

#define N_NODES    50000
#define N_G_EDGES  400000
#define N_LG_EDGES 600000
#define OUT_FEATS  64
#define EPSV       0.001f
#define PI_F       3.14159265358979323846f
#define HPI_F      1.57079632679489662f
#define FXSCALE    512.0f
#define INV_FXSCALE (1.0f/512.0f)

// kH roles: 256 blocks (R9-proven)
#define LG_CH   16
#define LG_BINS 50000
#define LG_W    12500
#define LG_EPC  37500
#define GH_B0   128
#define GH_CH   16
#define GH_W    12500
#define GH_EPC  25000
#define PK_B0   144
#define PK_GPB  3572

// scatter: block-local counting sort -> coalesced payload
#define NBUCK 256
#define NPB   196
#define SPB   (NPB*4)
#define EPB   2344           // 256*2344 = 600064 >= 600000

// ws layout (bytes):
//   kk8   u8 [400000]       @ 0           (   400,000)
//   R     u64[400000]       @ 400,000     ( 3,200,000)
//   clg   u32[128*12500]    @ 3,600,000   ( 6,400,000)
//   cg    u32[16*12500]     @ 10,000,000  (   800,000)
//   invg  f32[50000]        @ 10,800,000  (   200,000)
//   prefT u32[256*257]      @ 11,000,000  (   263,168)
//   grecs uint4[600064]     @ 11,263,168  ( 9,601,024)   (16B aligned)
// total 20,864,192

// ---------------- kH: balanced histograms + kk8 pack (R9-proven) ----------
__global__ __launch_bounds__(1024) void kH(const int* __restrict__ an,
                                           const int* __restrict__ gsrc,
                                           const int* __restrict__ gdst,
                                           const int* __restrict__ lgsrc,
                                           u8*  __restrict__ kk8,
                                           u32* __restrict__ clg,
                                           u32* __restrict__ cg) {
    __shared__ u32 hist[LG_W];
    const int tid = threadIdx.x;
    const int bid = blockIdx.x;

    if (bid < GH_B0) {
        const int cc = bid & 15, r = bid >> 4;
        const int lo = r * LG_BINS;
        for (int w = tid; w < LG_W; w += 1024) hist[w] = 0u;
        __syncthreads();
        const int s0 = cc * LG_EPC;
        for (int e = s0 + tid; e < s0 + LG_EPC; e += 1024) {
            unsigned lb = (unsigned)(lgsrc[e] - lo);
            if (lb < (unsigned)LG_BINS)
                atomicAdd(&hist[lb >> 2], 1u << (8 * (lb & 3)));
        }
        __syncthreads();
        u32* dst = clg + (size_t)bid * LG_W;
        for (int w = tid; w < LG_W; w += 1024) dst[w] = hist[w];
    } else if (bid < PK_B0) {
        const int cc = bid - GH_B0;
        for (int w = tid; w < GH_W; w += 1024) hist[w] = 0u;
        __syncthreads();
        const int s0 = cc * GH_EPC;
        for (int g = s0 + tid; g < s0 + GH_EPC; g += 1024) {
            int n = gsrc[g];
            atomicAdd(&hist[n >> 2], 1u << (8 * (n & 3)));
        }
        __syncthreads();
        u32* dst = cg + (size_t)cc * GH_W;
        for (int w = tid; w < GH_W; w += 1024) dst[w] = hist[w];
    } else {
        const int g0 = (bid - PK_B0) * PK_GPB;
        const int g1 = (g0 + PK_GPB < N_G_EDGES) ? g0 + PK_GPB : N_G_EDGES;
        for (int g = g0 + tid; g < g1; g += 1024)
            kk8[g] = (u8)(an[gsrc[g]] | (an[gdst[g]] << 4));
    }
}

// ---------------- kB: R records + inv_g (R9-proven) -----------------------
__global__ __launch_bounds__(1024) void kB(const int* __restrict__ gsrc,
                                           const u8*  __restrict__ kk8,
                                           const u32* __restrict__ clg,
                                           const u32* __restrict__ cg,
                                           u64* __restrict__ R,
                                           float* __restrict__ invg) {
    const int i = blockIdx.x * 1024 + threadIdx.x;
    for (int g = i; g < N_G_EDGES; g += 256 * 1024) {
        int r = g / LG_BINS, lb = g - r * LG_BINS;
        int w = lb >> 2, sh = 8 * (lb & 3);
        const u32* base = clg + (size_t)(r * LG_CH) * LG_W + w;
        u32 c = 0;
#pragma unroll
        for (int cc = 0; cc < LG_CH; ++cc) c += (base[(size_t)cc * LG_W] >> sh) & 0xffu;
        float inv = 1.0f / (float)(c < 1u ? 1u : c);
        R[g] = ((u64)__float_as_uint(inv) << 32) | ((u64)(u32)gsrc[g] << 8) | (u64)kk8[g];
    }
    for (int n = i; n < N_NODES; n += 256 * 1024) {
        int w = n >> 2, sh = 8 * (n & 3);
        u32 c = 0;
#pragma unroll
        for (int cc = 0; cc < GH_CH; ++cc) c += (cg[(size_t)cc * GH_W + w] >> sh) & 0xffu;
        invg[n] = 1.0f / (float)(c < 1u ? 1u : c);
    }
}

// ---------------- kC1: edge compute + LDS counting-sort, coalesced out ----
__global__ __launch_bounds__(1024, 1) void kC1(const int* __restrict__ lgsrc,
                                               const int* __restrict__ lgdst,
                                               const float* __restrict__ costheta,
                                               const float* __restrict__ dnr,
                                               const float* __restrict__ pa,
                                               const float* __restrict__ pb,
                                               const float* __restrict__ pc,
                                               const float* __restrict__ pd,
                                               const u8*  __restrict__ kk8,
                                               const u64* __restrict__ R,
                                               uint4* __restrict__ grecs,
                                               u32* __restrict__ prefT) {
    __shared__ uint4 rec[EPB];      // 37.5 KB
    __shared__ u32 lcnt[NBUCK];
    __shared__ u32 pref[NBUCK + 1];
    const int tid = threadIdx.x;
    const int bid = blockIdx.x;
    if (tid < NBUCK) lcnt[tid] = 0u;

    // Taylor coeffs (R9-proven): theta = pi/2 - ct; ang ~ A0 + d*(A1 + d*A2), d = -ct
    float A0[4], A1[4], A2[4], DD[4];
#pragma unroll
    for (int h = 0; h < 4; ++h) {
        float a = pa[h], B = fmodf(pb[h], PI_F), c = pc[h], d = pd[h];
        float K = a * HPI_F + B;
        float ck = cosf(K), sk = sinf(K);
        float u0 = 0.5f * (1.0f + ck);
        float f0 = powf(u0, c);
        float g1 = (-0.5f * a * sk) / u0;
        float u2 = -0.25f * a * a * ck;
        float g2 = u2 / u0 - 0.5f * g1 * g1;
        A0[h] = f0;
        A1[h] = f0 * c * g1;
        A2[h] = f0 * (c * g2 + 0.5f * c * c * g1 * g1);
        DD[h] = d;
    }
    __syncthreads();

    const int e0 = bid * EPB;
    const int e1 = (e0 + EPB < N_LG_EDGES) ? e0 + EPB : N_LG_EDGES;
    u64 q0 = 0, q1 = 0, q2 = 0;
    u32 m0 = 0, m1 = 0, m2 = 0;

#define COMPUTE_EDGE(IT, QV, MV)                                                  \
    {                                                                             \
        int e = e0 + IT * 1024 + tid;                                             \
        if (e < e1) {                                                             \
            u64 rr = R[lgsrc[e]];                                                 \
            int ka = (int)(rr & 0xf);                                             \
            int kb = (int)((rr >> 4) & 0xf);                                      \
            int node = (int)((rr >> 8) & 0xffff);                                 \
            float inv = __uint_as_float((u32)(rr >> 32));                         \
            int kd = kk8[lgdst[e]] >> 4;                                          \
            int key = ((ka == kd) ? 2 : 0) + ((kb == ka && kb == kd) ? 1 : 0);    \
            float ct = fminf(fmaxf(costheta[e], -EPSV), EPSV);                    \
            float del = -ct;                                                      \
            float dn2 = dnr[e]; dn2 *= dn2;                                       \
            float s = inv * FXSCALE;                                              \
            u64 q = 0;                                                            \
            _Pragma("unroll")                                                     \
            for (int h = 0; h < 4; ++h) {                                         \
                float ang = A0[h] + del * (A1[h] + del * A2[h]);                  \
                float rad = __expf(-DD[h] * dn2);                                 \
                q |= (u64)(u32)(ang * rad * s + 0.5f) << (16 * h);                \
            }                                                                     \
            int bucket = node / NPB;                                              \
            int slot = (node - bucket * NPB) * 4 + key;                           \
            u32 rank = atomicAdd(&lcnt[bucket], 1u);                              \
            QV = q;                                                               \
            MV = 0x80000000u | (rank << 18) | ((u32)bucket << 10) | (u32)slot;    \
        }                                                                         \
    }

    COMPUTE_EDGE(0, q0, m0)
    COMPUTE_EDGE(1, q1, m1)
    COMPUTE_EDGE(2, q2, m2)
#undef COMPUTE_EDGE

    __syncthreads();
    // exclusive prefix over bucket counts
    if (tid < NBUCK) pref[tid + 1] = lcnt[tid];
    if (tid == 0) pref[0] = 0u;
    __syncthreads();
    for (int off = 1; off < 256; off <<= 1) {
        u32 add = 0;
        if (tid < 256 && tid >= off) add = pref[tid - off + 1];
        __syncthreads();
        if (tid < 256) pref[tid + 1] += add;
        __syncthreads();
    }

    // place records bucket-sorted in LDS
#define PLACE(QV, MV)                                                             \
    if (MV & 0x80000000u) {                                                       \
        u32 bk = (MV >> 10) & 0xffu;                                              \
        u32 pos = pref[bk] + ((MV >> 18) & 0x1fffu);                              \
        rec[pos] = make_uint4((u32)QV, (u32)(QV >> 32), MV & 0x3ffu, 0u);         \
    }
    PLACE(q0, m0)
    PLACE(q1, m1)
    PLACE(q2, m2)
#undef PLACE
    __syncthreads();

    // coalesced payload + prefix-table writes
    const u32 btot = pref[256];
    uint4* dst = grecs + (size_t)bid * EPB;
    for (u32 i = tid; i < btot; i += 1024) dst[i] = rec[i];
    if (tid <= 256) prefT[bid * 257 + tid] = pref[tid];
}

// ---------------- kC2: compact gather + fused output ----------------------
__global__ __launch_bounds__(1024, 1) void kC2(const uint4* __restrict__ grecs,
                                               const u32* __restrict__ prefT,
                                               const float* __restrict__ inv_g,
                                               const float* __restrict__ VT,
                                               float* __restrict__ out) {
    __shared__ u64 ts[SPB];
    __shared__ u32 spref[257];
    __shared__ u32 sstart[256];
    __shared__ float vt_s[1024];
    const int tid = threadIdx.x;
    const int b = blockIdx.x;

    for (int i = tid; i < SPB; i += 1024) ts[i] = 0ull;
    if (tid < 256) {
        u32 a = prefT[tid * 257 + b];
        u32 c = prefT[tid * 257 + b + 1];
        sstart[tid] = a;
        spref[tid + 1] = c - a;
    }
    if (tid == 0) spref[0] = 0u;
    vt_s[tid] = VT[tid];
    __syncthreads();

    for (int off = 1; off < 256; off <<= 1) {
        u32 add = 0;
        if (tid < 256 && tid >= off) add = spref[tid - off + 1];
        __syncthreads();
        if (tid < 256) spref[tid + 1] += add;
        __syncthreads();
    }
    const u32 total = spref[256];

    for (u32 i = tid; i < total; i += 1024) {
        int lo = 0, hi = 256;
        while (hi - lo > 1) {
            int mid = (lo + hi) >> 1;
            if (spref[mid] <= i) lo = mid; else hi = mid;
        }
        u32 rank = i - spref[lo];
        uint4 r4 = grecs[(size_t)lo * EPB + sstart[lo] + rank];
        u64 q = (u64)r4.x | ((u64)r4.y << 32);
        atomicAdd(&ts[r4.z], q);
    }
    __syncthreads();

    const int n0 = b * NPB;
    for (int j = tid; j < NPB * OUT_FEATS; j += 1024) {
        int nl = j >> 6, f = j & 63;
        int n = n0 + nl;
        if (n < N_NODES) {
            float acc = 0.0f;
#pragma unroll
            for (int k = 0; k < 4; ++k) {
                u64 t = ts[nl * 4 + k];
#pragma unroll
                for (int h = 0; h < 4; ++h) {
                    float tv = (float)((u32)(t >> (16 * h)) & 0xffffu);
                    acc += vt_s[k * 256 + f * 4 + h] * tv;
                }
            }
            out[n * OUT_FEATS + f] = acc * INV_FXSCALE * inv_g[n];
        }
    }
}

extern "C" void kernel_launch(void* const* d_in, const int* in_sizes, int n_in,
                              void* d_out, int out_size, void* d_ws, size_t ws_size,
                              hipStream_t stream) {
    const int*   an       = (const int*)d_in[0];
    const int*   gsrc     = (const int*)d_in[1];
    const int*   gdst     = (const int*)d_in[2];
    const int*   lgsrc    = (const int*)d_in[3];
    const int*   lgdst    = (const int*)d_in[4];
    const float* costheta = (const float*)d_in[5];
    const float* dnr      = (const float*)d_in[6];
    const float* pa       = (const float*)d_in[7];
    const float* pb       = (const float*)d_in[8];
    const float* pc       = (const float*)d_in[9];
    const float* pd       = (const float*)d_in[10];
    const float* vt       = (const float*)d_in[11];
    float* out = (float*)d_out;

    char* ws = (char*)d_ws;
    u8*    kk8   = (u8*)   (ws + 0);
    u64*   R     = (u64*)  (ws + 400000);
    u32*   clg   = (u32*)  (ws + 3600000);
    u32*   cg    = (u32*)  (ws + 10000000);
    float* invg  = (float*)(ws + 10800000);
    u32*   prefT = (u32*)  (ws + 11000000);
    uint4* grecs = (uint4*)(ws + 11263168);

    kH<<<dim3(256), dim3(1024), 0, stream>>>(an, gsrc, gdst, lgsrc, kk8, clg, cg);
    kB<<<dim3(256), dim3(1024), 0, stream>>>(gsrc, kk8, clg, cg, R, invg);
    kC1<<<dim3(256), dim3(1024), 0, stream>>>(
        lgsrc, lgdst, costheta, dnr, pa, pb, pc, pd, kk8, R, grecs, prefT);
    kC2<<<dim3(256), dim3(1024), 0, stream>>>(grecs, prefT, invg, vt, out);
}

// Round 11
// 54.447 us; speedup vs baseline: 11.7408x; 1.0129x over previous
//
#include <hip/hip_runtime.h>
#include <math.h>

typedef unsigned long long u64;
typedef unsigned int u32;
typedef unsigned short u16;
typedef unsigned char u8;

#define N_NODES    50000
#define N_G_EDGES  400000
#define N_LG_EDGES 600000
#define OUT_FEATS  64
#define EPSV       0.001f
#define PI_F       3.14159265358979323846f
#define HPI_F      1.57079632679489662f
#define FXSCALE    512.0f
#define INV_FXSCALE (1.0f/512.0f)

// ---- K1 roles (512 blocks) ----
#define SB_N    256        // [0,256): ls-bucket sort, EPB1 edges each
#define EPB1    2344       // 256*2344 = 600064 >= 600000
#define LH_B0   256        // [256,384): lg histogram, 16 chunks x 8 ranges
#define LG_CH   16
#define LG_BINS 50000
#define LG_W    12500
#define LG_EPC  37500
#define GH_B0   384        // [384,400): g histogram, 16 chunks full range
#define GH_CH   16
#define GH_W    12500
#define GH_EPC  25000
#define PK_B0   400        // [400,512): kk8 pack
#define PK_GPB  3572       // 112*3572 = 400064
#define K1_GRID 512

// ---- ls-buckets ----
#define WID   1564         // word-aligned (1564 = 4*391); 256*1564 = 400384 >= 400000
#define NLSB  256
// ---- node buckets ----
#define NPB   196
#define SPB   (NPB*4)
#define CAP2  2816         // per-ls-bucket record capacity (lambda~2346, +9.5 sigma)

// ws layout (bytes):
//   kk8    u8 [400000]       @ 0           (   400,000)
//   clg    u32[128*12500]    @ 400,000     ( 6,400,000)
//   cg     u32[16*12500]     @ 6,800,000   (   800,000)
//   srecs  uint4[256*2344]   @ 7,600,000   ( 9,601,024)
//   prefT1 u32[256*257]      @ 17,201,024  (   263,168)
//   mrecs  uint4[256*2816]   @ 17,464,192  (11,534,336)
//   prefT2 u32[256*257]      @ 28,998,528  (   263,168)
// total 29,261,696

// ============ K1: sort-by-ls + histograms + pack (4 roles) ============
__global__ __launch_bounds__(1024) void k1(const int* __restrict__ an,
                                           const int* __restrict__ gsrc,
                                           const int* __restrict__ gdst,
                                           const int* __restrict__ lgsrc,
                                           const int* __restrict__ lgdst,
                                           const float* __restrict__ costheta,
                                           const float* __restrict__ dnr,
                                           u8*  __restrict__ kk8,
                                           u32* __restrict__ clg,
                                           u32* __restrict__ cg,
                                           uint4* __restrict__ srecs,
                                           u32* __restrict__ prefT1) {
    __shared__ u32 smem[12800];   // 51.2 KB, aliased per role
    const int tid = threadIdx.x;
    const int bid = blockIdx.x;

    if (bid < SB_N) {
        // ---- ls-bucket counting sort (no gathers, all coalesced) ----
        uint4* rec = (uint4*)smem;            // 2344*4 = 9376 words
        u32* lcnt = smem + 9600;              // 256
        u32* pref = smem + 9872;              // 257
        if (tid < 256) lcnt[tid] = 0u;
        __syncthreads();
        const int e0 = bid * EPB1;
        const int e1 = (e0 + EPB1 < N_LG_EDGES) ? e0 + EPB1 : N_LG_EDGES;
        u32 meta[3]; uint4 val[3];
#pragma unroll
        for (int it = 0; it < 3; ++it) {
            meta[it] = 0u;
            int e = e0 + it * 1024 + tid;
            if (e < e1) {
                int ls = lgsrc[e];
                int ld = lgdst[e];
                float ct = costheta[e];
                float dn = dnr[e];
                u32 bk = (u32)ls / WID;
                u32 rank = atomicAdd(&lcnt[bk], 1u);
                val[it] = make_uint4(__float_as_uint(ct), __float_as_uint(dn),
                                     (u32)ld, (u32)ls);
                meta[it] = 0x80000000u | (rank << 8) | bk;
            }
        }
        __syncthreads();
        if (tid < 256) pref[tid + 1] = lcnt[tid];
        if (tid == 0) pref[0] = 0u;
        __syncthreads();
        for (int off = 1; off < 256; off <<= 1) {
            u32 add = 0;
            if (tid < 256 && tid >= off) add = pref[tid - off + 1];
            __syncthreads();
            if (tid < 256) pref[tid + 1] += add;
            __syncthreads();
        }
#pragma unroll
        for (int it = 0; it < 3; ++it) {
            if (meta[it] & 0x80000000u) {
                u32 bk = meta[it] & 0xffu;
                u32 pos = pref[bk] + ((meta[it] >> 8) & 0x1fffu);
                rec[pos] = val[it];
            }
        }
        __syncthreads();
        const u32 btot = pref[256];
        uint4* dst = srecs + (size_t)bid * EPB1;
        for (u32 i = tid; i < btot; i += 1024) dst[i] = rec[i];
        if (tid <= 256) prefT1[bid * 257 + tid] = pref[tid];
    } else if (bid < GH_B0) {
        // ---- lg histogram (chunk cc, range r) ----
        const int bid2 = bid - LH_B0;
        const int cc = bid2 & 15, r = bid2 >> 4;
        const int lo = r * LG_BINS;
        for (int w = tid; w < LG_W; w += 1024) smem[w] = 0u;
        __syncthreads();
        const int s0 = cc * LG_EPC;
        for (int e = s0 + tid; e < s0 + LG_EPC; e += 1024) {
            unsigned lb = (unsigned)(lgsrc[e] - lo);
            if (lb < (unsigned)LG_BINS)
                atomicAdd(&smem[lb >> 2], 1u << (8 * (lb & 3)));
        }
        __syncthreads();
        u32* dst = clg + (size_t)bid2 * LG_W;
        for (int w = tid; w < LG_W; w += 1024) dst[w] = smem[w];
    } else if (bid < PK_B0) {
        // ---- g histogram (chunk cc, full 50k-bin range) ----
        const int cc = bid - GH_B0;
        for (int w = tid; w < GH_W; w += 1024) smem[w] = 0u;
        __syncthreads();
        const int s0 = cc * GH_EPC;
        for (int g = s0 + tid; g < s0 + GH_EPC; g += 1024) {
            int n = gsrc[g];
            atomicAdd(&smem[n >> 2], 1u << (8 * (n & 3)));
        }
        __syncthreads();
        u32* dst = cg + (size_t)cc * GH_W;
        for (int w = tid; w < GH_W; w += 1024) dst[w] = smem[w];
    } else {
        // ---- kk8 pack ----
        const int g0 = (bid - PK_B0) * PK_GPB;
        const int g1 = (g0 + PK_GPB < N_G_EDGES) ? g0 + PK_GPB : N_G_EDGES;
        for (int g = g0 + tid; g < g1; g += 1024)
            kk8[g] = (u8)(an[gsrc[g]] | (an[gdst[g]] << 4));
    }
}

// ============ K2: per ls-window compute + node-bucket sort ============
__global__ __launch_bounds__(1024) void k2(const int* __restrict__ gsrc,
                                           const u8*  __restrict__ kk8,
                                           const u32* __restrict__ clg,
                                           const uint4* __restrict__ srecs,
                                           const u32* __restrict__ prefT1,
                                           const float* __restrict__ pa,
                                           const float* __restrict__ pb,
                                           const float* __restrict__ pc,
                                           const float* __restrict__ pd,
                                           uint4* __restrict__ mrecs,
                                           u32* __restrict__ prefT2) {
    __shared__ uint4 rec[CAP2];     // 45 KB
    __shared__ float invw[WID];
    __shared__ u16   nodew[WID];
    __shared__ u8    kkw[WID];
    __shared__ u32 sstart[256];
    __shared__ u32 spref[257];
    __shared__ u32 lcnt[256];
    __shared__ u32 pref2[257];
    const int tid = threadIdx.x;
    const int b = blockIdx.x;
    const int lo = b * WID;

    // coalesced window build: inv(clg chunk-sum), node(gsrc), kk8
    for (int i = tid; i < WID; i += 1024) {
        int ls = lo + i;
        float inv = 0.0f; u16 nd = 0; u8 kw = 0;
        if (ls < N_G_EDGES) {
            int r = ls / LG_BINS, lb = ls - r * LG_BINS;
            int w = lb >> 2, sh = 8 * (lb & 3);
            const u32* base = clg + (size_t)(r * LG_CH) * LG_W + w;
            u32 c = 0;
#pragma unroll
            for (int cc = 0; cc < LG_CH; ++cc) c += (base[(size_t)cc * LG_W] >> sh) & 0xffu;
            inv = 1.0f / (float)(c < 1u ? 1u : c);
            nd = (u16)gsrc[ls];
            kw = kk8[ls];
        }
        invw[i] = inv; nodew[i] = nd; kkw[i] = kw;
    }
    if (tid < 256) {
        u32 a = prefT1[tid * 257 + b];
        u32 c2 = prefT1[tid * 257 + b + 1];
        sstart[tid] = a; spref[tid + 1] = c2 - a; lcnt[tid] = 0u;
    }
    if (tid == 0) spref[0] = 0u;
    __syncthreads();
    for (int off = 1; off < 256; off <<= 1) {
        u32 add = 0;
        if (tid < 256 && tid >= off) add = spref[tid - off + 1];
        __syncthreads();
        if (tid < 256) spref[tid + 1] += add;
        __syncthreads();
    }
    const u32 total = spref[256];

    // Taylor coeffs (R9/R10-proven): theta = pi/2 - ct, ang ~ A0+d*(A1+d*A2), d=-ct
    float A0[4], A1[4], A2[4], DD[4];
#pragma unroll
    for (int h = 0; h < 4; ++h) {
        float a = pa[h], B = fmodf(pb[h], PI_F), c = pc[h], d = pd[h];
        float K = a * HPI_F + B;
        float ck = cosf(K), sk = sinf(K);
        float u0 = 0.5f * (1.0f + ck);
        float f0 = powf(u0, c);
        float g1 = (-0.5f * a * sk) / u0;
        float u2 = -0.25f * a * a * ck;
        float g2 = u2 / u0 - 0.5f * g1 * g1;
        A0[h] = f0;
        A1[h] = f0 * c * g1;
        A2[h] = f0 * (c * g2 + 0.5f * c * c * g1 * g1);
        DD[h] = d;
    }

    u64 qv[3]; u32 mv[3];
#pragma unroll
    for (int it = 0; it < 3; ++it) {
        mv[it] = 0u;
        u32 i = (u32)(it * 1024 + tid);
        if (i < total) {
            int l2 = 0, h2 = 256;
            while (h2 - l2 > 1) {
                int mid = (l2 + h2) >> 1;
                if (spref[mid] <= i) l2 = mid; else h2 = mid;
            }
            uint4 r4 = srecs[(size_t)l2 * EPB1 + sstart[l2] + (i - spref[l2])];
            float ct = __uint_as_float(r4.x);
            float dn = __uint_as_float(r4.y);
            u32 ld = r4.z;
            int li = (int)r4.w - lo;
            float inv = invw[li];
            int node = (int)nodew[li];
            u32 kw = kkw[li];
            int ka = (int)(kw & 0xfu);
            int kb = (int)(kw >> 4);
            int kd = kk8[ld] >> 4;                 // only remaining gather (400KB, L2)
            int key = ((ka == kd) ? 2 : 0) + ((kb == ka && kb == kd) ? 1 : 0);
            ct = fminf(fmaxf(ct, -EPSV), EPSV);
            float del = -ct;
            float dn2 = dn * dn;
            float s = inv * FXSCALE;
            u64 q = 0;
#pragma unroll
            for (int h = 0; h < 4; ++h) {
                float ang = A0[h] + del * (A1[h] + del * A2[h]);
                float rad = __expf(-DD[h] * dn2);
                q |= (u64)(u32)(ang * rad * s + 0.5f) << (16 * h);
            }
            u32 nb = (u32)node / NPB;
            u32 slot = ((u32)node - nb * NPB) * 4u + (u32)key;
            u32 rank = atomicAdd(&lcnt[nb], 1u);
            qv[it] = q;
            mv[it] = 0x80000000u | (rank << 18) | (nb << 10) | slot;
        }
    }
    __syncthreads();
    if (tid < 256) pref2[tid + 1] = lcnt[tid];
    if (tid == 0) pref2[0] = 0u;
    __syncthreads();
    for (int off = 1; off < 256; off <<= 1) {
        u32 add = 0;
        if (tid < 256 && tid >= off) add = pref2[tid - off + 1];
        __syncthreads();
        if (tid < 256) pref2[tid + 1] += add;
        __syncthreads();
    }
#pragma unroll
    for (int it = 0; it < 3; ++it) {
        if (mv[it] & 0x80000000u) {
            u32 nb = (mv[it] >> 10) & 0xffu;
            u32 pos = pref2[nb] + ((mv[it] >> 18) & 0x1fffu);
            if (pos < CAP2)
                rec[pos] = make_uint4((u32)qv[it], (u32)(qv[it] >> 32),
                                      mv[it] & 0x3ffu, 0u);
        }
    }
    __syncthreads();
    u32 t2 = pref2[256]; if (t2 > CAP2) t2 = CAP2;
    uint4* dst = mrecs + (size_t)b * CAP2;
    for (u32 i = tid; i < t2; i += 1024) dst[i] = rec[i];
    if (tid <= 256) {
        u32 v = pref2[tid];
        prefT2[b * 257 + tid] = (v < CAP2) ? v : CAP2;
    }
}

// ============ K3: per node-bucket gather + invg + fused output ============
__global__ __launch_bounds__(1024) void k3(const uint4* __restrict__ mrecs,
                                           const u32* __restrict__ prefT2,
                                           const u32* __restrict__ cg,
                                           const float* __restrict__ VT,
                                           float* __restrict__ out) {
    __shared__ u64 ts[SPB];
    __shared__ u32 sstart[256];
    __shared__ u32 spref[257];
    __shared__ float vt_s[1024];
    __shared__ float invg_s[NPB];
    const int tid = threadIdx.x;
    const int nb = blockIdx.x;

    for (int i = tid; i < SPB; i += 1024) ts[i] = 0ull;
    vt_s[tid] = VT[tid];
    if (tid < NPB) {
        int n = nb * NPB + tid;
        float iv = 0.0f;
        if (n < N_NODES) {
            int w = n >> 2, sh = 8 * (n & 3);
            u32 c = 0;
#pragma unroll
            for (int cc = 0; cc < GH_CH; ++cc) c += (cg[(size_t)cc * GH_W + w] >> sh) & 0xffu;
            iv = 1.0f / (float)(c < 1u ? 1u : c);
        }
        invg_s[tid] = iv;
    }
    if (tid < 256) {
        u32 a = prefT2[tid * 257 + nb];
        u32 c2 = prefT2[tid * 257 + nb + 1];
        sstart[tid] = a; spref[tid + 1] = c2 - a;
    }
    if (tid == 0) spref[0] = 0u;
    __syncthreads();
    for (int off = 1; off < 256; off <<= 1) {
        u32 add = 0;
        if (tid < 256 && tid >= off) add = spref[tid - off + 1];
        __syncthreads();
        if (tid < 256) spref[tid + 1] += add;
        __syncthreads();
    }
    const u32 total = spref[256];

    for (u32 i = tid; i < total; i += 1024) {
        int l2 = 0, h2 = 256;
        while (h2 - l2 > 1) {
            int mid = (l2 + h2) >> 1;
            if (spref[mid] <= i) l2 = mid; else h2 = mid;
        }
        uint4 r4 = mrecs[(size_t)l2 * CAP2 + sstart[l2] + (i - spref[l2])];
        atomicAdd(&ts[r4.z], (u64)r4.x | ((u64)r4.y << 32));
    }
    __syncthreads();

    const int n0 = nb * NPB;
    for (int j = tid; j < NPB * OUT_FEATS; j += 1024) {
        int nl = j >> 6, f = j & 63;
        int n = n0 + nl;
        if (n < N_NODES) {
            float acc = 0.0f;
#pragma unroll
            for (int k = 0; k < 4; ++k) {
                u64 t = ts[nl * 4 + k];
#pragma unroll
                for (int h = 0; h < 4; ++h) {
                    float tv = (float)((u32)(t >> (16 * h)) & 0xffffu);
                    acc += vt_s[k * 256 + f * 4 + h] * tv;
                }
            }
            out[n * OUT_FEATS + f] = acc * INV_FXSCALE * invg_s[nl];
        }
    }
}

extern "C" void kernel_launch(void* const* d_in, const int* in_sizes, int n_in,
                              void* d_out, int out_size, void* d_ws, size_t ws_size,
                              hipStream_t stream) {
    const int*   an       = (const int*)d_in[0];
    const int*   gsrc     = (const int*)d_in[1];
    const int*   gdst     = (const int*)d_in[2];
    const int*   lgsrc    = (const int*)d_in[3];
    const int*   lgdst    = (const int*)d_in[4];
    const float* costheta = (const float*)d_in[5];
    const float* dnr      = (const float*)d_in[6];
    const float* pa       = (const float*)d_in[7];
    const float* pb       = (const float*)d_in[8];
    const float* pc       = (const float*)d_in[9];
    const float* pd       = (const float*)d_in[10];
    const float* vt       = (const float*)d_in[11];
    float* out = (float*)d_out;

    char* ws = (char*)d_ws;
    u8*    kk8    = (u8*)   (ws + 0);
    u32*   clg    = (u32*)  (ws + 400000);
    u32*   cg     = (u32*)  (ws + 6800000);
    uint4* srecs  = (uint4*)(ws + 7600000);
    u32*   prefT1 = (u32*)  (ws + 17201024);
    uint4* mrecs  = (uint4*)(ws + 17464192);
    u32*   prefT2 = (u32*)  (ws + 28998528);

    k1<<<dim3(K1_GRID), dim3(1024), 0, stream>>>(
        an, gsrc, gdst, lgsrc, lgdst, costheta, dnr, kk8, clg, cg, srecs, prefT1);
    k2<<<dim3(NLSB), dim3(1024), 0, stream>>>(
        gsrc, kk8, clg, srecs, prefT1, pa, pb, pc, pd, mrecs, prefT2);
    k3<<<dim3(256), dim3(1024), 0, stream>>>(mrecs, prefT2, cg, vt, out);
}